// Round 20
// baseline (523.777 us; speedup 1.0000x reference)
//
#include <hip/hip_runtime.h>
#include <math.h>

#define CIN   3
#define DD    32
#define HH    128
#define WW    128
#define COUTC 24
#define HP    126
#define WP    126
#define PLANE (HH * WW)            // 16384

#define NTH     256                // 4 waves = 4 channels per block
#define LDSROW  68                 // floats per staged row (17 float4)
#define RPC     6                  // input rows per cin (4 out rows + 2)
#define NSLOT   306                // 18 rows x 17 float4 slots
#define SLICE_STRIDE 1280          // floats per slice buffer (padded from 1224)

typedef const __attribute__((address_space(1))) void global_cv;
typedef __attribute__((address_space(3))) void shared_v;

// One depth slice. Slot of conv[j] = j%3. At slice d: S0=d%3 (zeroed, kd=0),
// S1=(d+2)%3 (kd=1 -> conv[d-1]), S2=(d+1)%3 (kd=2 -> completes conv[d-2]).
// Lane owns 1 output row x 4 cols: ring[4][3]+mn[4] keeps live regs ~40 so
// the 64-VGPR cap (launch_bounds min-waves=4) holds WITHOUT spilling.
template<int S0, int S1, int S2>
__device__ __forceinline__ void do_slice(
    int d,
    const float* __restrict__ g0, const float* __restrict__ g1, int act1,
    float* lds_wb0, float* lds_wb1,       // wave-uniform slot bases (buffer 0)
    const float (&w)[81],                 // wave-uniform -> SGPRs
    float (&ring)[4][3], float (&mn)[4],
    const float* __restrict__ rbase)
{
  __syncthreads();                        // buf[d&1] staged; prior reads done

  if (d + 1 < DD) {                       // async-stage next slice
    const int nb = (d + 1) & 1;
    __builtin_amdgcn_global_load_lds(
        (global_cv*)(g0 + (size_t)(d + 1) * PLANE),
        (shared_v*)(lds_wb0 + nb * SLICE_STRIDE), 16, 0, 0);
    if (act1)
      __builtin_amdgcn_global_load_lds(
          (global_cv*)(g1 + (size_t)(d + 1) * PLANE),
          (shared_v*)(lds_wb1 + nb * SLICE_STRIDE), 16, 0, 0);
  }

  const float* bp = rbase + (d & 1) * SLICE_STRIDE;

  #pragma unroll
  for (int q = 0; q < 4; ++q) ring[q][S0] = 0.0f;

  #pragma unroll
  for (int ci = 0; ci < CIN; ++ci) {
    #pragma unroll
    for (int kh = 0; kh < 3; ++kh) {
      // row offsets (ci*RPC+kh)*LDSROW are compile-time ds_read immediates
      const float* rp = bp + (ci * RPC + kh) * LDSROW;
      float4 a  = *(const float4*)rp;
      float2 b2 = *(const float2*)(rp + 4);
      float p[6] = {a.x, a.y, a.z, a.w, b2.x, b2.y};
      #pragma unroll
      for (int kw = 0; kw < 3; ++kw) {
        const float wv0 = w[ci * 27 + 0 + kh * 3 + kw];    // kd=0 -> S0
        const float wv1 = w[ci * 27 + 9 + kh * 3 + kw];    // kd=1 -> S1
        const float wv2 = w[ci * 27 + 18 + kh * 3 + kw];   // kd=2 -> S2
        #pragma unroll
        for (int q = 0; q < 4; ++q) {
          const float xv = p[kw + q];
          ring[q][S0] = fmaf(xv, wv0, ring[q][S0]);
          ring[q][S1] = fmaf(xv, wv1, ring[q][S1]);
          ring[q][S2] = fmaf(xv, wv2, ring[q][S2]);
        }
      }
    }
  }

  if (d >= 2) {                           // S2 = completed conv[d-2]
    #pragma unroll
    for (int q = 0; q < 4; ++q) mn[q] = fminf(mn[q], ring[q][S2]);
  }
}

__global__ void __launch_bounds__(NTH, 4)
conv3d_min_kernel(const float* __restrict__ x,
                  const float* __restrict__ wgt,
                  const float* __restrict__ bias,
                  float* __restrict__ out)
{
  __shared__ __align__(16) float lds[2 * SLICE_STRIDE];   // 10.2 KB

  const int t    = threadIdx.x;
  const int lane = t & 63;
  const int wv   = t >> 6;                 // 4 waves, one channel each
  // channel is wave-uniform: force SGPR so weight loads become s_load
  const int ch   = __builtin_amdgcn_readfirstlane(blockIdx.y * 4 + wv);
  const int r    = lane >> 4;              // output row 0..3 in tile
  const int g    = lane & 15;              // col-group (4 cols)
  const int wt   = blockIdx.x & 1;
  const int ht   = blockIdx.x >> 1;        // 32 h-tiles of 4 rows
  const int bb   = blockIdx.z;
  const int hp0  = ht * 4;
  const int w0   = wt * 64;

  // ---- channel weights (wave-uniform -> SGPR file) ----
  float w[81];
  {
    const float* wc = wgt + ch * 81;
    #pragma unroll
    for (int i = 0; i < 81; ++i) w[i] = wc[i];
  }
  const float bval = bias[ch];

  // ---- staging: 306 slots; slot t for all threads, slot 256+t for t<50 ----
  // global_load_lds writes wave-uniform base + lane*16: slot (64*wv + lane).
  // LDSROW=68=17*4: float offset r*68 + j*4 == 4*(17r+j) == 4*slot. ----
  const int s1   = t + NTH;
  const int act1 = (s1 < NSLOT);           // only wave 0, lanes 0..49
  const int r0 = t / 17,  j0 = t - r0 * 17;
  const int r1 = s1 / 17, j1 = s1 - r1 * 17;
  const int ci0 = r0 / RPC, rr0 = r0 - ci0 * RPC;
  const int ci1 = r1 / RPC, rr1 = r1 - ci1 * RPC;
  int grow0 = hp0 + rr0; grow0 = grow0 > 127 ? 127 : grow0;  // feeds only invalid rows
  int grow1 = hp0 + rr1; grow1 = grow1 > 127 ? 127 : grow1;
  int gc0 = w0 + j0 * 4; gc0 = gc0 > 124 ? 124 : gc0;        // keeps 16B align
  int gc1 = w0 + j1 * 4; gc1 = gc1 > 124 ? 124 : gc1;
  const float* g0 = x + (size_t)(bb * CIN + ci0) * (DD * PLANE) + grow0 * WW + gc0;
  const float* g1 = x + (size_t)(bb * CIN + ci1) * (DD * PLANE) + grow1 * WW + gc1;

  // wave-uniform LDS slot bases (floats)
  float* lds_wb0 = lds + 256 * wv;          // 64 slots * 4 floats per wave
  float* lds_wb1 = lds + 1024;              // slots 256.. (wave 0 only)

  // lane's LDS read base: its output row r, col 4g (kh/ci offsets are imms)
  const float* rbase = lds + r * LDSROW + g * 4;

  float ring[4][3];
  float mn[4];
  #pragma unroll
  for (int q = 0; q < 4; ++q) {
    mn[q] = INFINITY;
    ring[q][0] = ring[q][1] = ring[q][2] = 0.0f;
  }

  // ---- prologue: async-stage slice 0 into buffer 0 ----
  __builtin_amdgcn_global_load_lds((global_cv*)g0, (shared_v*)lds_wb0, 16, 0, 0);
  if (act1)
    __builtin_amdgcn_global_load_lds((global_cv*)g1, (shared_v*)lds_wb1, 16, 0, 0);

  // ---- stream 32 slices; ring slots compile-time (period 3) ----
  for (int d0 = 0; d0 < 30; d0 += 3) {
    do_slice<0,2,1>(d0,     g0, g1, act1, lds_wb0, lds_wb1, w, ring, mn, rbase);
    do_slice<1,0,2>(d0 + 1, g0, g1, act1, lds_wb0, lds_wb1, w, ring, mn, rbase);
    do_slice<2,1,0>(d0 + 2, g0, g1, act1, lds_wb0, lds_wb1, w, ring, mn, rbase);
  }
  do_slice<0,2,1>(30, g0, g1, act1, lds_wb0, lds_wb1, w, ring, mn, rbase);
  do_slice<1,0,2>(31, g0, g1, act1, lds_wb0, lds_wb1, w, ring, mn, rbase);

  // ---- epilogue: bias + store logits (softmax = kernel 2) ----
  const int orow = hp0 + r;
  if (orow < HP) {
    const int ocol = w0 + g * 4;
    float* op = out + ((size_t)(bb * COUTC + ch) * HP + orow) * WP + ocol;
    if (ocol + 3 < WP) {
      float4 ov = make_float4(mn[0] + bval, mn[1] + bval,
                              mn[2] + bval, mn[3] + bval);
      *(float4*)op = ov;
    } else {
      #pragma unroll
      for (int cc = 0; cc < 4; ++cc)
        if (ocol + cc < WP) op[cc] = mn[cc] + bval;
    }
  }
}

// ---- kernel 2: in-place softmax over the 24 channels ----
__global__ void __launch_bounds__(256)
softmax_ch_kernel(float* __restrict__ out)
{
  const int idx = blockIdx.x * 256 + threadIdx.x;
  const int npx = 16 * HP * WP;            // 254016
  if (idx >= npx) return;
  const int b  = idx / (HP * WP);
  const int hw = idx - b * (HP * WP);
  float* p = out + (size_t)b * COUTC * HP * WP + hw;

  float v[COUTC];
  float mx = -INFINITY;
  #pragma unroll
  for (int c = 0; c < COUTC; ++c) {
    v[c] = p[(size_t)c * HP * WP];
    mx = fmaxf(mx, v[c]);
  }
  float s = 0.0f;
  #pragma unroll
  for (int c = 0; c < COUTC; ++c) {
    v[c] = __expf(v[c] - mx);
    s += v[c];
  }
  const float rcp = 1.0f / s;
  #pragma unroll
  for (int c = 0; c < COUTC; ++c)
    p[(size_t)c * HP * WP] = v[c] * rcp;
}

extern "C" void kernel_launch(void* const* d_in, const int* in_sizes, int n_in,
                              void* d_out, int out_size, void* d_ws, size_t ws_size,
                              hipStream_t stream)
{
  const float* x    = (const float*)d_in[0];
  const float* wgt  = (const float*)d_in[1];
  const float* bias = (const float*)d_in[2];
  float* out = (float*)d_out;

  dim3 grid1(64, 6, 16);                   // (wt + 2*ht, ch-group, batch)
  hipLaunchKernelGGL(conv3d_min_kernel, grid1, dim3(NTH), 0, stream,
                     x, wgt, bias, out);

  const int npx = 16 * HP * WP;
  dim3 grid2((npx + 255) / 256);
  hipLaunchKernelGGL(softmax_ch_kernel, grid2, dim3(256), 0, stream, out);
}

// Round 24
// 495.908 us; speedup vs baseline: 1.0562x; 1.0562x over previous
//
#include <hip/hip_runtime.h>
#include <math.h>

#define CIN   3
#define DD    32
#define HH    128
#define WW    128
#define COUTC 24
#define HP    126
#define WP    126
#define PLANE (HH * WW)            // 16384

#define NTH     256                // 4 waves = 4 channels per block
#define LDSROW  68                 // floats per staged row (17 float4)
#define RPC     10                 // input rows per cin (8 out rows + 2)
#define SLICE_STRIDE 2048          // floats per slice buffer (512 slots; 510 used)
#define NSLOT   510                // 30 rows x 17 float4 slots

typedef const __attribute__((address_space(1))) void global_cv;
typedef __attribute__((address_space(3))) void shared_v;

// Apply one input row (6 dwords in p) to output row o with kernel row kh.
template<int SA, int SB, int SC>
__device__ __forceinline__ void tap(int o, int kh, int ci,
    const float (&w)[81], const float (&p)[6], float (&ring)[8][3])
{
  #pragma unroll
  for (int kw = 0; kw < 3; ++kw) {
    const float wv0 = w[ci * 27 + 0 + kh * 3 + kw];   // kd=0 -> SA
    const float wv1 = w[ci * 27 + 9 + kh * 3 + kw];   // kd=1 -> SB
    const float wv2 = w[ci * 27 + 18 + kh * 3 + kw];  // kd=2 -> SC
    #pragma unroll
    for (int cc = 0; cc < 4; ++cc) {
      const float xv = p[kw + cc];
      ring[o * 4 + cc][SA] = fmaf(xv, wv0, ring[o * 4 + cc][SA]);
      ring[o * 4 + cc][SB] = fmaf(xv, wv1, ring[o * 4 + cc][SB]);
      ring[o * 4 + cc][SC] = fmaf(xv, wv2, ring[o * 4 + cc][SC]);
    }
  }
}

// One depth slice. Slot of conv[j] = j%3. At slice d: S0=d%3 (zeroed, kd=0),
// S1=(d+2)%3 (kd=1 -> conv[d-1]), S2=(d+1)%3 (kd=2 -> completes conv[d-2]).
// Staging is async global->LDS (no VGPR round-trip, no ds_writes): issued
// right after the barrier, drained by the NEXT barrier's vmcnt(0).
template<int S0, int S1, int S2>
__device__ __forceinline__ void do_slice(
    int d,
    const float* __restrict__ g0, const float* __restrict__ g1, int act1,
    float* lds_wb0, float* lds_wb1,       // wave-uniform slot bases (buffer 0)
    const float (&w)[81],                 // wave-uniform -> SGPRs
    float (&ring)[8][3], float (&mn)[8],
    const float* __restrict__ rbase)
{
  __syncthreads();                        // buf[d&1] staged; prior reads done

  if (d + 1 < DD) {                       // async-stage next slice
    const int nb = (d + 1) & 1;
    __builtin_amdgcn_global_load_lds(
        (global_cv*)(g0 + (size_t)(d + 1) * PLANE),
        (shared_v*)(lds_wb0 + nb * SLICE_STRIDE), 16, 0, 0);
    if (act1)
      __builtin_amdgcn_global_load_lds(
          (global_cv*)(g1 + (size_t)(d + 1) * PLANE),
          (shared_v*)(lds_wb1 + nb * SLICE_STRIDE), 16, 0, 0);
  }

  const float* bp = rbase + (d & 1) * SLICE_STRIDE;

  #pragma unroll
  for (int q = 0; q < 8; ++q) ring[q][S0] = 0.0f;

  #pragma unroll
  for (int ci = 0; ci < CIN; ++ci) {
    #pragma unroll
    for (int j = 0; j < 4; ++j) {        // input row rbase+j; pairs o+kh==j
      const float* rp = bp + (ci * RPC + j) * LDSROW;
      float4 a  = *(const float4*)rp;
      float2 b2 = *(const float2*)(rp + 4);
      float p[6] = {a.x, a.y, a.z, a.w, b2.x, b2.y};
      if (j == 0) { tap<S0,S1,S2>(0, 0, ci, w, p, ring); }
      if (j == 1) { tap<S0,S1,S2>(0, 1, ci, w, p, ring);
                    tap<S0,S1,S2>(1, 0, ci, w, p, ring); }
      if (j == 2) { tap<S0,S1,S2>(0, 2, ci, w, p, ring);
                    tap<S0,S1,S2>(1, 1, ci, w, p, ring); }
      if (j == 3) { tap<S0,S1,S2>(1, 2, ci, w, p, ring); }
    }
  }

  if (d >= 2) {                           // S2 = completed conv[d-2]
    #pragma unroll
    for (int q = 0; q < 8; ++q) mn[q] = fminf(mn[q], ring[q][S2]);
  }
}

__global__ void __launch_bounds__(NTH, 2)
conv3d_min_kernel(const float* __restrict__ x,
                  const float* __restrict__ wgt,
                  const float* __restrict__ bias,
                  float* __restrict__ out)
{
  __shared__ __align__(16) float lds[2 * SLICE_STRIDE];   // 16 KB

  const int t    = threadIdx.x;
  const int lane = t & 63;
  const int wv   = t >> 6;                 // 4 waves, one channel each
  // channel is wave-uniform: force SGPR so weight loads become s_load
  const int ch   = __builtin_amdgcn_readfirstlane(blockIdx.y * 4 + wv);
  const int rp_  = lane >> 4;              // row-pair 0..3
  const int g    = lane & 15;              // col-group (4 cols)
  const int rbase_r = rp_ * 2;             // top output row of the pair
  const int wt   = blockIdx.x & 1;
  const int ht   = blockIdx.x >> 1;        // 16 h-tiles of 8 rows
  const int bb   = blockIdx.z;
  const int hp0  = ht * 8;
  const int w0   = wt * 64;

  // ---- channel weights (wave-uniform -> SGPR file) ----
  float w[81];
  {
    const float* wc = wgt + ch * 81;
    #pragma unroll
    for (int i = 0; i < 81; ++i) w[i] = wc[i];
  }
  const float bval = bias[ch];

  // ---- staging: slot s = thread for s<256; slot 256+t for t<254 ----
  // global_load_lds writes wave-uniform base + lane*16: slot (64*wv + lane)
  // for load 0 and (256 + 64*wv + lane) for load 1 -- linear in lane.
  // LDSROW=68=17*4 makes the linear slot layout == row-major layout:
  // float offset r*68 + j*4 == 4*(17r+j) == 4*slot. ----
  const int s1   = t + NTH;
  const int act1 = (s1 < NSLOT);
  const int r0 = t / 17,  j0 = t - r0 * 17;
  const int r1 = s1 / 17, j1 = s1 - r1 * 17;
  const int ci0 = r0 / RPC, rr0 = r0 - ci0 * RPC;
  const int ci1 = r1 / RPC, rr1 = r1 - ci1 * RPC;
  int grow0 = hp0 + rr0; grow0 = grow0 > 127 ? 127 : grow0;  // feeds only invalid rows
  int grow1 = hp0 + rr1; grow1 = grow1 > 127 ? 127 : grow1;
  int gc0 = w0 + j0 * 4; gc0 = gc0 > 124 ? 124 : gc0;        // keeps 16B align
  int gc1 = w0 + j1 * 4; gc1 = gc1 > 124 ? 124 : gc1;
  const float* g0 = x + (size_t)(bb * CIN + ci0) * (DD * PLANE) + grow0 * WW + gc0;
  const float* g1 = x + (size_t)(bb * CIN + ci1) * (DD * PLANE) + grow1 * WW + gc1;

  // wave-uniform LDS slot bases (floats): load0 slots [64wv..), load1 [256+64wv..)
  float* lds_wb0 = lds + 256 * wv;          // 64 slots * 4 floats
  float* lds_wb1 = lds + 1024 + 256 * wv;

  // lane's LDS read base: its top input row, col 4g
  const float* rbase = lds + rbase_r * LDSROW + g * 4;

  float ring[8][3];
  float mn[8];
  #pragma unroll
  for (int q = 0; q < 8; ++q) {
    mn[q] = INFINITY;
    ring[q][0] = ring[q][1] = ring[q][2] = 0.0f;
  }

  // ---- prologue: async-stage slice 0 into buffer 0 ----
  __builtin_amdgcn_global_load_lds((global_cv*)g0, (shared_v*)lds_wb0, 16, 0, 0);
  if (act1)
    __builtin_amdgcn_global_load_lds((global_cv*)g1, (shared_v*)lds_wb1, 16, 0, 0);

  // ---- stream 32 slices; ring slots compile-time (period 3) ----
  for (int d0 = 0; d0 < 30; d0 += 3) {
    do_slice<0,2,1>(d0,     g0, g1, act1, lds_wb0, lds_wb1, w, ring, mn, rbase);
    do_slice<1,0,2>(d0 + 1, g0, g1, act1, lds_wb0, lds_wb1, w, ring, mn, rbase);
    do_slice<2,1,0>(d0 + 2, g0, g1, act1, lds_wb0, lds_wb1, w, ring, mn, rbase);
  }
  do_slice<0,2,1>(30, g0, g1, act1, lds_wb0, lds_wb1, w, ring, mn, rbase);
  do_slice<1,0,2>(31, g0, g1, act1, lds_wb0, lds_wb1, w, ring, mn, rbase);

  // ---- epilogue: bias + store logits (softmax = kernel 2) ----
  #pragma unroll
  for (int o = 0; o < 2; ++o) {
    const int orow = hp0 + rbase_r + o;
    if (orow < HP) {
      const int ocol = w0 + g * 4;
      float* op = out + ((size_t)(bb * COUTC + ch) * HP + orow) * WP + ocol;
      if (ocol + 3 < WP) {
        float4 ov = make_float4(mn[o*4+0] + bval, mn[o*4+1] + bval,
                                mn[o*4+2] + bval, mn[o*4+3] + bval);
        *(float4*)op = ov;
      } else {
        #pragma unroll
        for (int cc = 0; cc < 4; ++cc)
          if (ocol + cc < WP) op[cc] = mn[o*4+cc] + bval;
      }
    }
  }
}

// ---- kernel 2: in-place softmax over the 24 channels ----
__global__ void __launch_bounds__(256)
softmax_ch_kernel(float* __restrict__ out)
{
  const int idx = blockIdx.x * 256 + threadIdx.x;
  const int npx = 16 * HP * WP;            // 254016
  if (idx >= npx) return;
  const int b  = idx / (HP * WP);
  const int hw = idx - b * (HP * WP);
  float* p = out + (size_t)b * COUTC * HP * WP + hw;

  float v[COUTC];
  float mx = -INFINITY;
  #pragma unroll
  for (int c = 0; c < COUTC; ++c) {
    v[c] = p[(size_t)c * HP * WP];
    mx = fmaxf(mx, v[c]);
  }
  float s = 0.0f;
  #pragma unroll
  for (int c = 0; c < COUTC; ++c) {
    v[c] = __expf(v[c] - mx);
    s += v[c];
  }
  const float rcp = 1.0f / s;
  #pragma unroll
  for (int c = 0; c < COUTC; ++c)
    p[(size_t)c * HP * WP] = v[c] * rcp;
}

extern "C" void kernel_launch(void* const* d_in, const int* in_sizes, int n_in,
                              void* d_out, int out_size, void* d_ws, size_t ws_size,
                              hipStream_t stream)
{
  const float* x    = (const float*)d_in[0];
  const float* wgt  = (const float*)d_in[1];
  const float* bias = (const float*)d_in[2];
  float* out = (float*)d_out;

  dim3 grid1(32, 6, 16);                   // (wt+ht, ch-group, batch)
  hipLaunchKernelGGL(conv3d_min_kernel, grid1, dim3(NTH), 0, stream,
                     x, wgt, bias, out);

  const int npx = 16 * HP * WP;
  dim3 grid2((npx + 255) / 256);
  hipLaunchKernelGGL(softmax_ch_kernel, grid2, dim3(256), 0, stream, out);
}